// Round 2
// baseline (604.401 us; speedup 1.0000x reference)
//
#include <hip/hip_runtime.h>
#include <hip/hip_bf16.h>

#define NB 32
#define NN 8400
#define NC 80
#define KPRE 512
#define MAXOUT 100

// ---------------- Kernel A: scores + per-image max ----------------
__global__ __launch_bounds__(256) void score_kernel(const float* __restrict__ pred,
                                                    float* __restrict__ scores,
                                                    unsigned* __restrict__ smax) {
    int b = blockIdx.y;
    int n = blockIdx.x * 256 + threadIdx.x;
    float s = 0.0f;
    if (n < NN) {
        const float* p = pred + ((size_t)b * NN + n) * 85;
        float obj = p[4];
        float cc = p[5];
        for (int c = 1; c < NC; c++) cc = fmaxf(cc, p[5 + c]);
        s = __fmul_rn(obj, cc);
        scores[(size_t)b * NN + n] = s;
    }
    // block max of nonneg floats via int bits
    unsigned bits = __float_as_uint(s);
    for (int o = 32; o > 0; o >>= 1) {
        unsigned other = (unsigned)__shfl_down((int)bits, o, 64);
        if (other > bits) bits = other;
    }
    __shared__ unsigned wmax[4];
    int lane = threadIdx.x & 63, wv = threadIdx.x >> 6;
    if (lane == 0) wmax[wv] = bits;
    __syncthreads();
    if (threadIdx.x == 0) {
        unsigned m = wmax[0];
        for (int i = 1; i < 4; i++) if (wmax[i] > m) m = wmax[i];
        atomicMax(&smax[b], m);
    }
}

// ---------------- bitonic sort (descending) in LDS ----------------
__device__ inline void bitonic_sort_desc(unsigned long long* buf, int M, int tid, int nthr) {
    for (int k = 2; k <= M; k <<= 1) {
        for (int j = k >> 1; j > 0; j >>= 1) {
            __syncthreads();
            for (int i = tid; i < M; i += nthr) {
                int ixj = i ^ j;
                if (ixj > i) {
                    unsigned long long a = buf[i];
                    unsigned long long c = buf[ixj];
                    bool up = ((i & k) == 0);
                    // descending overall: blocks with (i&k)==0 keep larger at i
                    bool sw = up ? (a < c) : (a > c);
                    if (sw) { buf[i] = c; buf[ixj] = a; }
                }
            }
        }
    }
    __syncthreads();
}

// ---------------- Kernel B: exact top-512 per image ----------------
// key = (score_bits << 32) | ~idx  for valid entries, else 0.
// Distinct keys -> total order; desc sort == top_k order (ties -> lower idx).
__global__ __launch_bounds__(1024) void select_kernel(const float* __restrict__ scores,
                                                      const unsigned* __restrict__ smax,
                                                      unsigned long long* __restrict__ topkeys) {
    int b = blockIdx.x;
    int tid = threadIdx.x;
    __shared__ unsigned long long buf[4096];
    __shared__ unsigned long long cand[2048];
    float conf = fminf(0.25f, __uint_as_float(smax[b]));

    for (int q = 0; q < 4; q++) {
        for (int m = tid; m < 4096; m += 1024) {
            unsigned long long key = 0ull;
            if (m < 2100) {
                int n = q * 2100 + m;
                float s = scores[(size_t)b * NN + n];
                if (s >= conf) {
                    key = ((unsigned long long)__float_as_uint(s) << 32) |
                          (unsigned long long)(unsigned)(~(unsigned)n);
                }
            }
            buf[m] = key;
        }
        bitonic_sort_desc(buf, 4096, tid, 1024);
        for (int r = tid; r < 512; r += 1024) cand[q * 512 + r] = buf[r];
        __syncthreads();
    }
    bitonic_sort_desc(cand, 2048, tid, 1024);
    for (int r = tid; r < 512; r += 1024) topkeys[(size_t)b * KPRE + r] = cand[r];
}

// ---------------- Kernel C: NMS + output ----------------
__global__ __launch_bounds__(512) void nms_kernel(const float* __restrict__ pred,
                                                  const unsigned long long* __restrict__ topkeys,
                                                  float* __restrict__ out) {
    int b = blockIdx.x;
    int t = threadIdx.x;
    __shared__ float4 sbox[KPRE];   // class-offset boxes (rounded coords, as reference)
    __shared__ float4 sraw[KPRE];   // un-offset boxes for output
    __shared__ float sobj[KPRE], scc[KPRE];
    __shared__ int   scp[KPRE], svalid[KPRE];
    __shared__ unsigned long long siou[KPRE * 8];
    __shared__ unsigned long long skeep[8];

    float* dets = out + (size_t)b * (MAXOUT * 7);
    float* mask = out + (size_t)NB * MAXOUT * 7 + (size_t)b * MAXOUT;
    for (int m = t; m < MAXOUT * 7; m += 512) dets[m] = 0.0f;
    if (t < MAXOUT) mask[t] = 0.0f;

    // gather + decode
    unsigned long long key = topkeys[(size_t)b * KPRE + t];
    int valid = ((unsigned)(key >> 32)) != 0u;
    unsigned n = ~(unsigned)key;
    if (!valid) n = 0;
    const float* p = pred + ((size_t)b * NN + n) * 85;
    float cx = p[0], cy = p[1], w = p[2], h = p[3], obj = p[4];
    float cc = p[5];
    int cp = 0;
    for (int c = 1; c < NC; c++) {
        float v = p[5 + c];
        if (v > cc) { cc = v; cp = c; }
    }
    float hw = __fmul_rn(w, 0.5f), hh = __fmul_rn(h, 0.5f);
    float x1 = cx - hw, y1 = cy - hh, x2 = cx + hw, y2 = cy + hh;
    float off = __fmul_rn((float)cp, 4096.0f);
    sraw[t] = make_float4(x1, y1, x2, y2);
    sbox[t] = make_float4(x1 + off, y1 + off, x2 + off, y2 + off);
    sobj[t] = obj; scc[t] = cc; scp[t] = cp; svalid[t] = valid;
    __syncthreads();

    // lower-triangle IoU>thr bitmatrix (bit j of word wd in row i; only j<i)
    for (int wi = t; wi < KPRE * 8; wi += 512) {
        int i = wi >> 3, wd = wi & 7;
        unsigned long long bits = 0ull;
        int j0 = wd * 64;
        if (j0 < i) {
            float4 bi = sbox[i];
            float ai = __fmul_rn(bi.z - bi.x, bi.w - bi.y);
            int jmax = i - j0; if (jmax > 64) jmax = 64;
            for (int jj = 0; jj < jmax; jj++) {
                float4 bj = sbox[j0 + jj];
                float xx1 = fmaxf(bi.x, bj.x);
                float yy1 = fmaxf(bi.y, bj.y);
                float xx2 = fminf(bi.z, bj.z);
                float yy2 = fminf(bi.w, bj.w);
                float iw = fmaxf(xx2 - xx1, 0.0f);
                float ih = fmaxf(yy2 - yy1, 0.0f);
                float inter = __fmul_rn(iw, ih);
                float aj = __fmul_rn(bj.z - bj.x, bj.w - bj.y);
                float uni = (ai + aj) - inter;
                float iou = inter / (uni + 1e-9f);
                if (iou > 0.45f) bits |= (1ull << jj);
            }
        }
        siou[(size_t)i * 8 + wd] = bits;
    }
    __syncthreads();

    // sequential greedy scan (reference-literal): keep mask in 8x64b words
    // held by lanes 0..7 of wave 0; row i tested vs current keep via ballot.
    if (t < 64) {
        unsigned long long keepW = 0ull;           // lane l (<8): keep bits [l*64, l*64+64)
        unsigned long long rw = (t < 8) ? siou[t] : 0ull;   // row 0, word t
        int v_i = svalid[0];
        for (int i = 0; i < KPRE; i++) {
            // prefetch next row word + validity (off the dependency chain)
            unsigned long long rw_nxt = 0ull;
            int v_nxt = 0;
            if (i + 1 < KPRE) {
                if (t < 8) rw_nxt = siou[(size_t)(i + 1) * 8 + t];
                v_nxt = svalid[i + 1];
            }
            bool hit = (rw & keepW) != 0ull;
            unsigned long long bal = __ballot(hit);
            int kept = v_i && (bal == 0ull);
            if (kept && t == (i >> 6)) keepW |= (1ull << (i & 63));
            rw = rw_nxt;
            v_i = v_nxt;
        }
        if (t < 8) skeep[t] = keepW;
    }
    __syncthreads();

    // rank kept rows, write first 100
    int w8 = t >> 6;
    unsigned long long kw = skeep[w8];
    int kept_t = (int)((kw >> (t & 63)) & 1ull);
    int rank = 0;
    for (int w2 = 0; w2 < w8; w2++) rank += __popcll(skeep[w2]);
    rank += __popcll(kw & ((1ull << (t & 63)) - 1ull));
    if (kept_t && rank < MAXOUT) {
        float4 rb = sraw[t];
        float* row = dets + rank * 7;
        row[0] = rb.x; row[1] = rb.y; row[2] = rb.z; row[3] = rb.w;
        row[4] = sobj[t]; row[5] = scc[t]; row[6] = (float)scp[t];
        mask[rank] = 1.0f;
    }
}

extern "C" void kernel_launch(void* const* d_in, const int* in_sizes, int n_in,
                              void* d_out, int out_size, void* d_ws, size_t ws_size,
                              hipStream_t stream) {
    const float* pred = (const float*)d_in[0];
    float* out = (float*)d_out;

    // ws layout: [0,128) smax; [128, 128+32*8400*4) scores; then topkeys
    unsigned* smax = (unsigned*)d_ws;
    float* scores = (float*)((char*)d_ws + 128);
    unsigned long long* topkeys = (unsigned long long*)((char*)d_ws + 128 + (size_t)NB * NN * 4);

    hipMemsetAsync(smax, 0, NB * sizeof(unsigned), stream);

    dim3 gA((NN + 255) / 256, NB);
    score_kernel<<<gA, 256, 0, stream>>>(pred, scores, smax);
    select_kernel<<<NB, 1024, 0, stream>>>(scores, smax, topkeys);
    nms_kernel<<<NB, 512, 0, stream>>>(pred, topkeys, out);
}

// Round 3
// 304.023 us; speedup vs baseline: 1.9880x; 1.9880x over previous
//
#include <hip/hip_runtime.h>
#include <hip/hip_bf16.h>

#define NB 32
#define NN 8400
#define NC 80
#define KPRE 512
#define MAXOUT 100

// ---------------- Kernel A: scores + per-image max (wave-cooperative LDS staging) ----------------
// block = 128 (2 waves); each wave stages 64 consecutive rows (64x85 floats, coalesced 256B/instr)
// then each lane reduces its own row from LDS (stride 85 dwords, gcd(85,32)=1 -> conflict-free).
__global__ __launch_bounds__(128) void score_kernel(const float* __restrict__ pred,
                                                    float* __restrict__ scores,
                                                    unsigned* __restrict__ smax) {
    int b = blockIdx.y;
    int w = threadIdx.x >> 6, lane = threadIdx.x & 63;
    int g = blockIdx.x * 2 + w;                  // 64-row group within image
    __shared__ float stg[2][64 * 85];
    size_t base = ((size_t)b * NN + (size_t)g * 64) * 85;
    size_t img_end = ((size_t)b + 1) * NN * 85;
    for (int k = lane; k < 64 * 85; k += 64) {
        size_t e = base + k;
        if (e >= img_end) e = img_end - 1;       // clamp tail (pad rows discarded below)
        stg[w][k] = pred[e];
    }
    __syncthreads();
    int row = g * 64 + lane;
    const float* r = &stg[w][lane * 85];
    float obj = r[4];
    float cc = r[5];
    for (int c = 6; c < 85; c++) cc = fmaxf(cc, r[c]);
    float s = __fmul_rn(obj, cc);
    if (row < NN) scores[(size_t)b * NN + row] = s;
    else s = 0.0f;                               // pad rows must not pollute the max
    unsigned bits = __float_as_uint(s);
    for (int o = 32; o > 0; o >>= 1) {
        unsigned other = (unsigned)__shfl_down((int)bits, o, 64);
        if (other > bits) bits = other;
    }
    __shared__ unsigned wmax[2];
    if (lane == 0) wmax[w] = bits;
    __syncthreads();
    if (threadIdx.x == 0) {
        unsigned m = wmax[0] > wmax[1] ? wmax[0] : wmax[1];
        atomicMax(&smax[b], m);
    }
}

// ---- wave-0 helper: largest bin B with suffix(B) >= T over hist[0..nb); R = T - suffix(B+1)
__device__ __forceinline__ void find_bin(const unsigned* hist, int nb, unsigned T, int lane,
                                         int* outB, unsigned* outR) {
    unsigned running = 0;
    for (int c = nb / 64 - 1; c >= 0; c--) {
        unsigned v = hist[c * 64 + lane];
        unsigned s = v;
        for (int off = 1; off < 64; off <<= 1) {
            unsigned u = (unsigned)__shfl_down((int)s, off, 64);
            if (lane + off < 64) s += u;
        }
        unsigned total0 = (unsigned)__shfl((int)s, 0, 64);   // chunk total
        if (total0 + running >= T) {
            unsigned long long mask = __ballot(s + running >= T);
            int m = 63 - __clzll(mask);                      // largest qualifying lane
            unsigned sm = (unsigned)__shfl((int)s, m, 64);
            unsigned vm = (unsigned)__shfl((int)v, m, 64);
            if (lane == 0) { *outB = c * 64 + m; *outR = T - (sm + running - vm); }
            return;
        }
        running += total0;
    }
    if (lane == 0) { *outB = 0; *outR = T; }   // unreachable for our targets
}

// ---------------- Kernel B: exact top-512 per image via LDS radix select ----------------
// key32 = score_bits if s>=conf else 0 (conf>0 -> valid <=> key!=0). Top-512 of all 8400 keys,
// ties at the boundary value broken by LOWEST index (== lax.top_k). Output 64-bit keys
// (key32<<32)|~idx in exact descending top_k order; zero-padded if fewer than 512 valid.
__global__ __launch_bounds__(256) void select_kernel(const float* __restrict__ scores,
                                                     const unsigned* __restrict__ smax,
                                                     unsigned long long* __restrict__ topkeys) {
    int b = blockIdx.x, t = threadIdx.x;
    __shared__ unsigned skey[NN];                 // 33.6 KB
    __shared__ unsigned hist[2048];               // 8 KB
    __shared__ unsigned long long list[KPRE];     // 4 KB
    __shared__ int elist[256];                    // boundary ties (1 KB)
    __shared__ int S_B[3];
    __shared__ unsigned S_T[3];
    __shared__ int S_cnt, S_ecnt;

    if (t == 0) { S_cnt = 0; S_ecnt = 0; }
    float conf = fminf(0.25f, __uint_as_float(smax[b]));
    for (int n = t; n < NN; n += 256) {
        float s = scores[(size_t)b * NN + n];
        skey[n] = (s >= conf) ? __float_as_uint(s) : 0u;
    }
    // pass A: bits[31:21]
    for (int i = t; i < 2048; i += 256) hist[i] = 0;
    __syncthreads();
    for (int n = t; n < NN; n += 256) atomicAdd(&hist[skey[n] >> 21], 1u);
    __syncthreads();
    if (t < 64) find_bin(hist, 2048, 512u, t, &S_B[0], &S_T[0]);
    __syncthreads();
    int B1 = S_B[0]; unsigned R1 = S_T[0];
    // pass B: bits[20:10] within top11==B1
    for (int i = t; i < 2048; i += 256) hist[i] = 0;
    __syncthreads();
    for (int n = t; n < NN; n += 256) {
        unsigned k = skey[n];
        if ((int)(k >> 21) == B1) atomicAdd(&hist[(k >> 10) & 0x7FFu], 1u);
    }
    __syncthreads();
    if (t < 64) find_bin(hist, 2048, R1, t, &S_B[1], &S_T[1]);
    __syncthreads();
    unsigned P = ((unsigned)B1 << 11) | (unsigned)S_B[1];
    unsigned R2 = S_T[1];
    // pass C: bits[9:0] within top22==P
    for (int i = t; i < 1024; i += 256) hist[i] = 0;
    __syncthreads();
    for (int n = t; n < NN; n += 256) {
        unsigned k = skey[n];
        if ((k >> 10) == P) atomicAdd(&hist[k & 0x3FFu], 1u);
    }
    __syncthreads();
    if (t < 64) find_bin(hist, 1024, R2, t, &S_B[2], &S_T[2]);
    __syncthreads();
    unsigned K32 = (P << 10) | (unsigned)S_B[2];
    unsigned R3 = S_T[2];
    // compact: definite winners (key > K32) unordered; gather boundary ties (key == K32)
    for (int n = t; n < NN; n += 256) {
        unsigned k = skey[n];
        if (k > K32) {
            int pos = atomicAdd(&S_cnt, 1);
            list[pos] = ((unsigned long long)k << 32) | (unsigned long long)(unsigned)(~(unsigned)n);
        }
        if (K32 != 0u && k == K32) {
            int ep = atomicAdd(&S_ecnt, 1);
            if (ep < 256) elist[ep] = n;   // >256 bit-identical boundary scores: ~impossible (random fp32)
        }
    }
    __syncthreads();
    // boundary: take the R3 smallest indices among the ties
    int ecnt = S_ecnt; if (ecnt > 256) ecnt = 256;
    if (t < ecnt) {
        int my = elist[t];
        int r = 0;
        for (int j = 0; j < ecnt; j++) r += (elist[j] < my) ? 1 : 0;
        if ((unsigned)r < R3) {
            int pos = atomicAdd(&S_cnt, 1);
            list[pos] = ((unsigned long long)K32 << 32) | (unsigned long long)(unsigned)(~(unsigned)my);
        }
    }
    __syncthreads();
    int cnt = S_cnt;                       // == 512 unless K32==0 (fewer than 512 valid)
    for (int i = cnt + t; i < KPRE; i += 256) list[i] = 0ull;
    __syncthreads();
    // exact rank via all-pairs compare (distinct nonzero keys -> permutation), write sorted
    unsigned long long K0 = list[t], K1 = list[t + 256];
    int r0 = 0, r1 = 0;
    for (int j = 0; j < KPRE; j++) {
        unsigned long long L = list[j];    // wave-uniform broadcast read
        r0 += (L > K0) ? 1 : 0;
        r1 += (L > K1) ? 1 : 0;
    }
    unsigned long long* out = topkeys + (size_t)b * KPRE;
    if (K0 != 0ull) out[r0] = K0; else out[t] = 0ull;
    if (K1 != 0ull) out[r1] = K1; else out[t + 256] = 0ull;
}

// ---------------- Kernel C: NMS + output ----------------
__global__ __launch_bounds__(512) void nms_kernel(const float* __restrict__ pred,
                                                  const unsigned long long* __restrict__ topkeys,
                                                  float* __restrict__ out) {
    int b = blockIdx.x;
    int t = threadIdx.x;
    __shared__ float4 sbox[KPRE];
    __shared__ float4 sraw[KPRE];
    __shared__ float sobj[KPRE], scc[KPRE];
    __shared__ int   scp[KPRE], svalid[KPRE];
    __shared__ unsigned long long siou[KPRE * 8];
    __shared__ unsigned long long skeep[8];

    float* dets = out + (size_t)b * (MAXOUT * 7);
    float* mask = out + (size_t)NB * MAXOUT * 7 + (size_t)b * MAXOUT;
    for (int m = t; m < MAXOUT * 7; m += 512) dets[m] = 0.0f;
    if (t < MAXOUT) mask[t] = 0.0f;

    unsigned long long key = topkeys[(size_t)b * KPRE + t];
    int valid = ((unsigned)(key >> 32)) != 0u;
    unsigned n = ~(unsigned)key;
    if (!valid) n = 0;
    const float* p = pred + ((size_t)b * NN + n) * 85;
    float cx = p[0], cy = p[1], w = p[2], h = p[3], obj = p[4];
    float cc = p[5];
    int cp = 0;
    for (int c = 1; c < NC; c++) {
        float v = p[5 + c];
        if (v > cc) { cc = v; cp = c; }
    }
    float hw = __fmul_rn(w, 0.5f), hh = __fmul_rn(h, 0.5f);
    float x1 = cx - hw, y1 = cy - hh, x2 = cx + hw, y2 = cy + hh;
    float off = __fmul_rn((float)cp, 4096.0f);
    sraw[t] = make_float4(x1, y1, x2, y2);
    sbox[t] = make_float4(x1 + off, y1 + off, x2 + off, y2 + off);
    sobj[t] = obj; scc[t] = cc; scp[t] = cp; svalid[t] = valid;
    __syncthreads();

    for (int wi = t; wi < KPRE * 8; wi += 512) {
        int i = wi >> 3, wd = wi & 7;
        unsigned long long bits = 0ull;
        int j0 = wd * 64;
        if (j0 < i) {
            float4 bi = sbox[i];
            float ai = __fmul_rn(bi.z - bi.x, bi.w - bi.y);
            int jmax = i - j0; if (jmax > 64) jmax = 64;
            for (int jj = 0; jj < jmax; jj++) {
                float4 bj = sbox[j0 + jj];
                float xx1 = fmaxf(bi.x, bj.x);
                float yy1 = fmaxf(bi.y, bj.y);
                float xx2 = fminf(bi.z, bj.z);
                float yy2 = fminf(bi.w, bj.w);
                float iw = fmaxf(xx2 - xx1, 0.0f);
                float ih = fmaxf(yy2 - yy1, 0.0f);
                float inter = __fmul_rn(iw, ih);
                float aj = __fmul_rn(bj.z - bj.x, bj.w - bj.y);
                float uni = (ai + aj) - inter;
                float iou = inter / (uni + 1e-9f);
                if (iou > 0.45f) bits |= (1ull << jj);
            }
        }
        siou[(size_t)i * 8 + wd] = bits;
    }
    __syncthreads();

    if (t < 64) {
        unsigned long long keepW = 0ull;
        unsigned long long rw = (t < 8) ? siou[t] : 0ull;
        int v_i = svalid[0];
        for (int i = 0; i < KPRE; i++) {
            unsigned long long rw_nxt = 0ull;
            int v_nxt = 0;
            if (i + 1 < KPRE) {
                if (t < 8) rw_nxt = siou[(size_t)(i + 1) * 8 + t];
                v_nxt = svalid[i + 1];
            }
            bool hit = (rw & keepW) != 0ull;
            unsigned long long bal = __ballot(hit);
            int kept = v_i && (bal == 0ull);
            if (kept && t == (i >> 6)) keepW |= (1ull << (i & 63));
            rw = rw_nxt;
            v_i = v_nxt;
        }
        if (t < 8) skeep[t] = keepW;
    }
    __syncthreads();

    int w8 = t >> 6;
    unsigned long long kw = skeep[w8];
    int kept_t = (int)((kw >> (t & 63)) & 1ull);
    int rank = 0;
    for (int w2 = 0; w2 < w8; w2++) rank += __popcll(skeep[w2]);
    rank += __popcll(kw & ((1ull << (t & 63)) - 1ull));
    if (kept_t && rank < MAXOUT) {
        float4 rb = sraw[t];
        float* row = dets + rank * 7;
        row[0] = rb.x; row[1] = rb.y; row[2] = rb.z; row[3] = rb.w;
        row[4] = sobj[t]; row[5] = scc[t]; row[6] = (float)scp[t];
        mask[rank] = 1.0f;
    }
}

extern "C" void kernel_launch(void* const* d_in, const int* in_sizes, int n_in,
                              void* d_out, int out_size, void* d_ws, size_t ws_size,
                              hipStream_t stream) {
    const float* pred = (const float*)d_in[0];
    float* out = (float*)d_out;

    unsigned* smax = (unsigned*)d_ws;
    float* scores = (float*)((char*)d_ws + 128);
    unsigned long long* topkeys = (unsigned long long*)((char*)d_ws + 128 + (size_t)NB * NN * 4);

    hipMemsetAsync(smax, 0, NB * sizeof(unsigned), stream);

    dim3 gA((NN + 127) / 128, NB);
    score_kernel<<<gA, 128, 0, stream>>>(pred, scores, smax);
    select_kernel<<<NB, 256, 0, stream>>>(scores, smax, topkeys);
    nms_kernel<<<NB, 512, 0, stream>>>(pred, topkeys, out);
}

// Round 4
// 280.072 us; speedup vs baseline: 2.1580x; 1.0855x over previous
//
#include <hip/hip_runtime.h>
#include <hip/hip_bf16.h>

#define NB 32
#define NN 8400
#define NC 80
#define KPRE 512
#define MAXOUT 100

// ---------------- Kernel A: scores + per-image max (wave-cooperative LDS staging) ----------------
__global__ __launch_bounds__(128) void score_kernel(const float* __restrict__ pred,
                                                    float* __restrict__ scores,
                                                    unsigned* __restrict__ smax) {
    int b = blockIdx.y;
    int w = threadIdx.x >> 6, lane = threadIdx.x & 63;
    int g = blockIdx.x * 2 + w;
    __shared__ float stg[2][64 * 85];
    size_t base = ((size_t)b * NN + (size_t)g * 64) * 85;
    size_t img_end = ((size_t)b + 1) * NN * 85;
    for (int k = lane; k < 64 * 85; k += 64) {
        size_t e = base + k;
        if (e >= img_end) e = img_end - 1;
        stg[w][k] = pred[e];
    }
    __syncthreads();
    int row = g * 64 + lane;
    const float* r = &stg[w][lane * 85];
    float obj = r[4];
    float cc = r[5];
    for (int c = 6; c < 85; c++) cc = fmaxf(cc, r[c]);
    float s = __fmul_rn(obj, cc);
    if (row < NN) scores[(size_t)b * NN + row] = s;
    else s = 0.0f;
    unsigned bits = __float_as_uint(s);
    for (int o = 32; o > 0; o >>= 1) {
        unsigned other = (unsigned)__shfl_down((int)bits, o, 64);
        if (other > bits) bits = other;
    }
    __shared__ unsigned wmax[2];
    if (lane == 0) wmax[w] = bits;
    __syncthreads();
    if (threadIdx.x == 0) {
        unsigned m = wmax[0] > wmax[1] ? wmax[0] : wmax[1];
        atomicMax(&smax[b], m);
    }
}

// ---- wave-0 helper: largest bin B with suffix(B) >= T over hist[0..nb); R = T - suffix(B+1)
__device__ __forceinline__ void find_bin(const unsigned* hist, int nb, unsigned T, int lane,
                                         int* outB, unsigned* outR) {
    unsigned running = 0;
    for (int c = nb / 64 - 1; c >= 0; c--) {
        unsigned v = hist[c * 64 + lane];
        unsigned s = v;
        for (int off = 1; off < 64; off <<= 1) {
            unsigned u = (unsigned)__shfl_down((int)s, off, 64);
            if (lane + off < 64) s += u;
        }
        unsigned total0 = (unsigned)__shfl((int)s, 0, 64);
        if (total0 + running >= T) {
            unsigned long long mask = __ballot(s + running >= T);
            int m = 63 - __clzll(mask);
            unsigned sm = (unsigned)__shfl((int)s, m, 64);
            unsigned vm = (unsigned)__shfl((int)v, m, 64);
            if (lane == 0) { *outB = c * 64 + m; *outR = T - (sm + running - vm); }
            return;
        }
        running += total0;
    }
    if (lane == 0) { *outB = 0; *outR = T; }
}

// ---------------- Kernel B: exact top-512 per image via LDS radix select ----------------
__global__ __launch_bounds__(256) void select_kernel(const float* __restrict__ scores,
                                                     const unsigned* __restrict__ smax,
                                                     unsigned long long* __restrict__ topkeys) {
    int b = blockIdx.x, t = threadIdx.x;
    __shared__ unsigned skey[NN];
    __shared__ unsigned hist[2048];
    __shared__ unsigned long long list[KPRE];
    __shared__ int elist[256];
    __shared__ int S_B[3];
    __shared__ unsigned S_T[3];
    __shared__ int S_cnt, S_ecnt;

    if (t == 0) { S_cnt = 0; S_ecnt = 0; }
    float conf = fminf(0.25f, __uint_as_float(smax[b]));
    for (int n = t; n < NN; n += 256) {
        float s = scores[(size_t)b * NN + n];
        skey[n] = (s >= conf) ? __float_as_uint(s) : 0u;
    }
    for (int i = t; i < 2048; i += 256) hist[i] = 0;
    __syncthreads();
    for (int n = t; n < NN; n += 256) atomicAdd(&hist[skey[n] >> 21], 1u);
    __syncthreads();
    if (t < 64) find_bin(hist, 2048, 512u, t, &S_B[0], &S_T[0]);
    __syncthreads();
    int B1 = S_B[0]; unsigned R1 = S_T[0];
    for (int i = t; i < 2048; i += 256) hist[i] = 0;
    __syncthreads();
    for (int n = t; n < NN; n += 256) {
        unsigned k = skey[n];
        if ((int)(k >> 21) == B1) atomicAdd(&hist[(k >> 10) & 0x7FFu], 1u);
    }
    __syncthreads();
    if (t < 64) find_bin(hist, 2048, R1, t, &S_B[1], &S_T[1]);
    __syncthreads();
    unsigned P = ((unsigned)B1 << 11) | (unsigned)S_B[1];
    unsigned R2 = S_T[1];
    for (int i = t; i < 1024; i += 256) hist[i] = 0;
    __syncthreads();
    for (int n = t; n < NN; n += 256) {
        unsigned k = skey[n];
        if ((k >> 10) == P) atomicAdd(&hist[k & 0x3FFu], 1u);
    }
    __syncthreads();
    if (t < 64) find_bin(hist, 1024, R2, t, &S_B[2], &S_T[2]);
    __syncthreads();
    unsigned K32 = (P << 10) | (unsigned)S_B[2];
    unsigned R3 = S_T[2];
    for (int n = t; n < NN; n += 256) {
        unsigned k = skey[n];
        if (k > K32) {
            int pos = atomicAdd(&S_cnt, 1);
            list[pos] = ((unsigned long long)k << 32) | (unsigned long long)(unsigned)(~(unsigned)n);
        }
        if (K32 != 0u && k == K32) {
            int ep = atomicAdd(&S_ecnt, 1);
            if (ep < 256) elist[ep] = n;
        }
    }
    __syncthreads();
    int ecnt = S_ecnt; if (ecnt > 256) ecnt = 256;
    if (t < ecnt) {
        int my = elist[t];
        int r = 0;
        for (int j = 0; j < ecnt; j++) r += (elist[j] < my) ? 1 : 0;
        if ((unsigned)r < R3) {
            int pos = atomicAdd(&S_cnt, 1);
            list[pos] = ((unsigned long long)K32 << 32) | (unsigned long long)(unsigned)(~(unsigned)my);
        }
    }
    __syncthreads();
    int cnt = S_cnt;
    for (int i = cnt + t; i < KPRE; i += 256) list[i] = 0ull;
    __syncthreads();
    unsigned long long K0 = list[t], K1 = list[t + 256];
    int r0 = 0, r1 = 0;
    for (int j = 0; j < KPRE; j++) {
        unsigned long long L = list[j];
        r0 += (L > K0) ? 1 : 0;
        r1 += (L > K1) ? 1 : 0;
    }
    unsigned long long* out = topkeys + (size_t)b * KPRE;
    if (K0 != 0ull) out[r0] = K0; else out[t] = 0ull;
    if (K1 != 0ull) out[r1] = K1; else out[t + 256] = 0ull;
}

// ---------------- Kernel C1: gather + decode top-512 ----------------
__global__ __launch_bounds__(512) void decode_kernel(const float* __restrict__ pred,
                                                     const unsigned long long* __restrict__ topkeys,
                                                     float4* __restrict__ boxoff,
                                                     float4* __restrict__ boxraw,
                                                     float4* __restrict__ meta) {
    int b = blockIdx.x, t = threadIdx.x;
    unsigned long long key = topkeys[(size_t)b * KPRE + t];
    int valid = ((unsigned)(key >> 32)) != 0u;
    unsigned n = ~(unsigned)key;
    if (!valid) n = 0;
    const float* p = pred + ((size_t)b * NN + n) * 85;
    float cx = p[0], cy = p[1], w = p[2], h = p[3], obj = p[4];
    float cc = p[5];
    int cp = 0;
    for (int c = 1; c < NC; c++) {
        float v = p[5 + c];
        if (v > cc) { cc = v; cp = c; }
    }
    float hw = __fmul_rn(w, 0.5f), hh = __fmul_rn(h, 0.5f);
    float x1 = cx - hw, y1 = cy - hh, x2 = cx + hw, y2 = cy + hh;
    float off = __fmul_rn((float)cp, 4096.0f);
    size_t o = (size_t)b * KPRE + t;
    boxraw[o] = make_float4(x1, y1, x2, y2);
    boxoff[o] = make_float4(x1 + off, y1 + off, x2 + off, y2 + off);
    meta[o] = make_float4(obj, cc, (float)cp, valid ? 1.0f : 0.0f);
}

// ---------------- Kernel C2: IoU bitmatrix build (massively parallel) ----------------
// grid (8 row-chunks, 32 images) x 256 thr. Thread = (row r, col-quarter q).
// Column iteration rotated by q*33 -> 4 quarters hit distinct banks (conflict-free).
__global__ __launch_bounds__(256) void iou_kernel(const float4* __restrict__ boxoff,
                                                  unsigned long long* __restrict__ ioug) {
    int b = blockIdx.y, t = threadIdx.x;
    int r = blockIdx.x * 64 + (t >> 2);
    int q = t & 3;
    __shared__ float4 sb[KPRE];
    for (int i = t; i < KPRE; i += 256) sb[i] = boxoff[(size_t)b * KPRE + i];
    __syncthreads();
    float4 bi = sb[r];
    float ai = __fmul_rn(bi.z - bi.x, bi.w - bi.y);
    unsigned long long w0 = 0ull, w1 = 0ull;
    int base = q * 128, rot = q * 33;
    for (int s = 0; s < 128; s++) {
        int jj = (s + rot) & 127;
        int jc = base + jj;
        float4 bj = sb[jc];
        float xx1 = fmaxf(bi.x, bj.x);
        float yy1 = fmaxf(bi.y, bj.y);
        float xx2 = fminf(bi.z, bj.z);
        float yy2 = fminf(bi.w, bj.w);
        float iw = fmaxf(xx2 - xx1, 0.0f);
        float ih = fmaxf(yy2 - yy1, 0.0f);
        float inter = __fmul_rn(iw, ih);
        float aj = __fmul_rn(bj.z - bj.x, bj.w - bj.y);
        float uni = (ai + aj) - inter;
        float iou = inter / (uni + 1e-9f);
        if (iou > 0.45f && jc < r) {
            if (jj < 64) w0 |= 1ull << jj;
            else         w1 |= 1ull << (jj - 64);
        }
    }
    size_t rowbase = ((size_t)(b << 9) + r) * 8 + q * 2;
    ioug[rowbase]     = w0;
    ioug[rowbase + 1] = w1;
}

// ---------------- Kernel C3: sequential greedy scan + output ----------------
__global__ __launch_bounds__(64) void scan_kernel(const unsigned long long* __restrict__ ioug,
                                                  const float4* __restrict__ boxraw,
                                                  const float4* __restrict__ meta,
                                                  float* __restrict__ out) {
    int b = blockIdx.x, t = threadIdx.x;
    __shared__ unsigned long long siou[KPRE * 8];   // 32 KB
    __shared__ unsigned long long svalm[8];
    __shared__ unsigned long long skeep[8];

    // stage bitmatrix global -> LDS (b128)
    const ulonglong2* src = (const ulonglong2*)(ioug + ((size_t)b << 12));
    ulonglong2* dst = (ulonglong2*)siou;
    for (int it = 0; it < 32; it++) dst[it * 64 + t] = src[it * 64 + t];
    // validity mask via ballot (8 groups of 64)
    for (int g = 0; g < 8; g++) {
        float v = meta[(size_t)(b << 9) + g * 64 + t].w;
        unsigned long long m = __ballot(v != 0.0f);
        if (t == 0) svalm[g] = m;
    }
    __syncthreads();

    // sequential greedy: keep mask 8x64b in lanes 0..7, ballot per row
    {
        unsigned long long keepW = 0ull;
        unsigned long long rw = (t < 8) ? siou[t] : 0ull;
        int v_i = (int)(svalm[0] & 1ull);
        for (int i = 0; i < KPRE; i++) {
            unsigned long long rw_nxt = 0ull;
            int v_nxt = 0;
            if (i + 1 < KPRE) {
                if (t < 8) rw_nxt = siou[(size_t)(i + 1) * 8 + t];
                v_nxt = (int)((svalm[(i + 1) >> 6] >> ((i + 1) & 63)) & 1ull);
            }
            bool hit = (rw & keepW) != 0ull;
            unsigned long long bal = __ballot(hit);
            int kept = v_i && (bal == 0ull);
            if (kept && t == (i >> 6)) keepW |= (1ull << (i & 63));
            rw = rw_nxt;
            v_i = v_nxt;
        }
        if (t < 8) skeep[t] = keepW;
    }
    __syncthreads();

    // zero output region
    float* dets = out + (size_t)b * (MAXOUT * 7);
    float* mask = out + (size_t)NB * MAXOUT * 7 + (size_t)b * MAXOUT;
    for (int m = t; m < MAXOUT * 7; m += 64) dets[m] = 0.0f;
    for (int m = t; m < MAXOUT; m += 64) mask[m] = 0.0f;

    // rank kept rows, gather decoded data, write first 100
    for (int c = t; c < KPRE; c += 64) {
        int w8 = c >> 6;
        unsigned long long kw = skeep[w8];
        int kept_c = (int)((kw >> (c & 63)) & 1ull);
        if (!kept_c) continue;
        int rank = 0;
        for (int w2 = 0; w2 < w8; w2++) rank += __popcll(skeep[w2]);
        rank += __popcll(kw & ((1ull << (c & 63)) - 1ull));
        if (rank < MAXOUT) {
            float4 rb = boxraw[(size_t)(b << 9) + c];
            float4 mt = meta[(size_t)(b << 9) + c];
            float* row = dets + rank * 7;
            row[0] = rb.x; row[1] = rb.y; row[2] = rb.z; row[3] = rb.w;
            row[4] = mt.x; row[5] = mt.y; row[6] = mt.z;
            mask[rank] = 1.0f;
        }
    }
}

extern "C" void kernel_launch(void* const* d_in, const int* in_sizes, int n_in,
                              void* d_out, int out_size, void* d_ws, size_t ws_size,
                              hipStream_t stream) {
    const float* pred = (const float*)d_in[0];
    float* out = (float*)d_out;

    // ws layout (bytes):
    char* ws = (char*)d_ws;
    unsigned* smax = (unsigned*)ws;                                   // 128
    float* scores = (float*)(ws + 128);                               // 32*8400*4 = 1,075,200
    unsigned long long* topkeys = (unsigned long long*)(ws + 1075328); // 131,072
    float4* boxoff = (float4*)(ws + 1206400);                         // 262,144
    float4* boxraw = (float4*)(ws + 1468544);                         // 262,144
    float4* meta   = (float4*)(ws + 1730688);                         // 262,144
    unsigned long long* ioug = (unsigned long long*)(ws + 1992832);   // 1,048,576  (total ~2.9 MB)

    hipMemsetAsync(smax, 0, NB * sizeof(unsigned), stream);

    dim3 gA((NN + 127) / 128, NB);
    score_kernel<<<gA, 128, 0, stream>>>(pred, scores, smax);
    select_kernel<<<NB, 256, 0, stream>>>(scores, smax, topkeys);
    decode_kernel<<<NB, 512, 0, stream>>>(pred, topkeys, boxoff, boxraw, meta);
    dim3 gI(8, NB);
    iou_kernel<<<gI, 256, 0, stream>>>(boxoff, ioug);
    scan_kernel<<<NB, 64, 0, stream>>>(ioug, boxraw, meta, out);
}

// Round 5
// 238.711 us; speedup vs baseline: 2.5319x; 1.1733x over previous
//
#include <hip/hip_runtime.h>
#include <hip/hip_bf16.h>

#define NB 32
#define NN 8400
#define NC 80
#define KPRE 512
#define MAXOUT 100

// ---------------- Kernel A: scores + per-image max (wave-cooperative LDS staging) ----------------
__global__ __launch_bounds__(128) void score_kernel(const float* __restrict__ pred,
                                                    float* __restrict__ scores,
                                                    unsigned* __restrict__ smax) {
    int b = blockIdx.y;
    int w = threadIdx.x >> 6, lane = threadIdx.x & 63;
    int g = blockIdx.x * 2 + w;
    __shared__ float stg[2][64 * 85];
    size_t base = ((size_t)b * NN + (size_t)g * 64) * 85;
    size_t img_end = ((size_t)b + 1) * NN * 85;
    for (int k = lane; k < 64 * 85; k += 64) {
        size_t e = base + k;
        if (e >= img_end) e = img_end - 1;
        stg[w][k] = pred[e];
    }
    __syncthreads();
    int row = g * 64 + lane;
    const float* r = &stg[w][lane * 85];
    float obj = r[4];
    float cc = r[5];
    for (int c = 6; c < 85; c++) cc = fmaxf(cc, r[c]);
    float s = __fmul_rn(obj, cc);
    if (row < NN) scores[(size_t)b * NN + row] = s;
    else s = 0.0f;
    unsigned bits = __float_as_uint(s);
    for (int o = 32; o > 0; o >>= 1) {
        unsigned other = (unsigned)__shfl_down((int)bits, o, 64);
        if (other > bits) bits = other;
    }
    __shared__ unsigned wmax[2];
    if (lane == 0) wmax[w] = bits;
    __syncthreads();
    if (threadIdx.x == 0) {
        unsigned m = wmax[0] > wmax[1] ? wmax[0] : wmax[1];
        atomicMax(&smax[b], m);
    }
}

// ---- wave-0 helper: largest bin B with suffix(B) >= T over hist[0..nb); R = T - suffix(B+1)
__device__ __forceinline__ void find_bin(const unsigned* hist, int nb, unsigned T, int lane,
                                         int* outB, unsigned* outR) {
    unsigned running = 0;
    for (int c = nb / 64 - 1; c >= 0; c--) {
        unsigned v = hist[c * 64 + lane];
        unsigned s = v;
        for (int off = 1; off < 64; off <<= 1) {
            unsigned u = (unsigned)__shfl_down((int)s, off, 64);
            if (lane + off < 64) s += u;
        }
        unsigned total0 = (unsigned)__shfl((int)s, 0, 64);
        if (total0 + running >= T) {
            unsigned long long mask = __ballot(s + running >= T);
            int m = 63 - __clzll(mask);
            unsigned sm = (unsigned)__shfl((int)s, m, 64);
            unsigned vm = (unsigned)__shfl((int)v, m, 64);
            if (lane == 0) { *outB = c * 64 + m; *outR = T - (sm + running - vm); }
            return;
        }
        running += total0;
    }
    if (lane == 0) { *outB = 0; *outR = T; }
}

// ---------------- Kernel B: exact top-512 per image via LDS radix select ----------------
__global__ __launch_bounds__(256) void select_kernel(const float* __restrict__ scores,
                                                     const unsigned* __restrict__ smax,
                                                     unsigned long long* __restrict__ topkeys,
                                                     int* __restrict__ nvalid) {
    int b = blockIdx.x, t = threadIdx.x;
    __shared__ unsigned skey[NN];
    __shared__ unsigned hist[2048];
    __shared__ unsigned long long list[KPRE];
    __shared__ int elist[256];
    __shared__ int S_B[3];
    __shared__ unsigned S_T[3];
    __shared__ int S_cnt, S_ecnt;

    if (t == 0) { S_cnt = 0; S_ecnt = 0; }
    float conf = fminf(0.25f, __uint_as_float(smax[b]));
    for (int n = t; n < NN; n += 256) {
        float s = scores[(size_t)b * NN + n];
        skey[n] = (s >= conf) ? __float_as_uint(s) : 0u;
    }
    for (int i = t; i < 2048; i += 256) hist[i] = 0;
    __syncthreads();
    for (int n = t; n < NN; n += 256) atomicAdd(&hist[skey[n] >> 21], 1u);
    __syncthreads();
    if (t < 64) find_bin(hist, 2048, 512u, t, &S_B[0], &S_T[0]);
    __syncthreads();
    int B1 = S_B[0]; unsigned R1 = S_T[0];
    for (int i = t; i < 2048; i += 256) hist[i] = 0;
    __syncthreads();
    for (int n = t; n < NN; n += 256) {
        unsigned k = skey[n];
        if ((int)(k >> 21) == B1) atomicAdd(&hist[(k >> 10) & 0x7FFu], 1u);
    }
    __syncthreads();
    if (t < 64) find_bin(hist, 2048, R1, t, &S_B[1], &S_T[1]);
    __syncthreads();
    unsigned P = ((unsigned)B1 << 11) | (unsigned)S_B[1];
    unsigned R2 = S_T[1];
    for (int i = t; i < 1024; i += 256) hist[i] = 0;
    __syncthreads();
    for (int n = t; n < NN; n += 256) {
        unsigned k = skey[n];
        if ((k >> 10) == P) atomicAdd(&hist[k & 0x3FFu], 1u);
    }
    __syncthreads();
    if (t < 64) find_bin(hist, 1024, R2, t, &S_B[2], &S_T[2]);
    __syncthreads();
    unsigned K32 = (P << 10) | (unsigned)S_B[2];
    unsigned R3 = S_T[2];
    for (int n = t; n < NN; n += 256) {
        unsigned k = skey[n];
        if (k > K32) {
            int pos = atomicAdd(&S_cnt, 1);
            list[pos] = ((unsigned long long)k << 32) | (unsigned long long)(unsigned)(~(unsigned)n);
        }
        if (K32 != 0u && k == K32) {
            int ep = atomicAdd(&S_ecnt, 1);
            if (ep < 256) elist[ep] = n;
        }
    }
    __syncthreads();
    int ecnt = S_ecnt; if (ecnt > 256) ecnt = 256;
    if (t < ecnt) {
        int my = elist[t];
        int r = 0;
        for (int j = 0; j < ecnt; j++) r += (elist[j] < my) ? 1 : 0;
        if ((unsigned)r < R3) {
            int pos = atomicAdd(&S_cnt, 1);
            list[pos] = ((unsigned long long)K32 << 32) | (unsigned long long)(unsigned)(~(unsigned)my);
        }
    }
    __syncthreads();
    int cnt = S_cnt;
    if (t == 0) nvalid[b] = cnt;
    for (int i = cnt + t; i < KPRE; i += 256) list[i] = 0ull;
    __syncthreads();
    unsigned long long K0 = list[t], K1 = list[t + 256];
    int r0 = 0, r1 = 0;
    for (int j = 0; j < KPRE; j++) {
        unsigned long long L = list[j];
        r0 += (L > K0) ? 1 : 0;
        r1 += (L > K1) ? 1 : 0;
    }
    unsigned long long* out = topkeys + (size_t)b * KPRE;
    if (K0 != 0ull) out[r0] = K0; else out[t] = 0ull;
    if (K1 != 0ull) out[r1] = K1; else out[t + 256] = 0ull;
}

// ---------------- Kernel C1: gather + decode top-512 ----------------
__global__ __launch_bounds__(512) void decode_kernel(const float* __restrict__ pred,
                                                     const unsigned long long* __restrict__ topkeys,
                                                     float4* __restrict__ boxoff,
                                                     float4* __restrict__ boxraw,
                                                     float4* __restrict__ meta) {
    int b = blockIdx.x, t = threadIdx.x;
    unsigned long long key = topkeys[(size_t)b * KPRE + t];
    int valid = ((unsigned)(key >> 32)) != 0u;
    unsigned n = ~(unsigned)key;
    if (!valid) n = 0;
    const float* p = pred + ((size_t)b * NN + n) * 85;
    float cx = p[0], cy = p[1], w = p[2], h = p[3], obj = p[4];
    float cc = p[5];
    int cp = 0;
    for (int c = 1; c < NC; c++) {
        float v = p[5 + c];
        if (v > cc) { cc = v; cp = c; }
    }
    float hw = __fmul_rn(w, 0.5f), hh = __fmul_rn(h, 0.5f);
    float x1 = cx - hw, y1 = cy - hh, x2 = cx + hw, y2 = cy + hh;
    float off = __fmul_rn((float)cp, 4096.0f);
    size_t o = (size_t)b * KPRE + t;
    boxraw[o] = make_float4(x1, y1, x2, y2);
    boxoff[o] = make_float4(x1 + off, y1 + off, x2 + off, y2 + off);
    meta[o] = make_float4(obj, cc, (float)cp, valid ? 1.0f : 0.0f);
}

// ---------------- Kernel C2: IoU bitmatrix build (massively parallel) ----------------
__global__ __launch_bounds__(256) void iou_kernel(const float4* __restrict__ boxoff,
                                                  unsigned long long* __restrict__ ioug) {
    int b = blockIdx.y, t = threadIdx.x;
    int r = blockIdx.x * 64 + (t >> 2);
    int q = t & 3;
    __shared__ float4 sb[KPRE];
    for (int i = t; i < KPRE; i += 256) sb[i] = boxoff[(size_t)b * KPRE + i];
    __syncthreads();
    float4 bi = sb[r];
    float ai = __fmul_rn(bi.z - bi.x, bi.w - bi.y);
    unsigned long long w0 = 0ull, w1 = 0ull;
    int base = q * 128, rot = q * 33;
    for (int s = 0; s < 128; s++) {
        int jj = (s + rot) & 127;
        int jc = base + jj;
        float4 bj = sb[jc];
        float xx1 = fmaxf(bi.x, bj.x);
        float yy1 = fmaxf(bi.y, bj.y);
        float xx2 = fminf(bi.z, bj.z);
        float yy2 = fminf(bi.w, bj.w);
        float iw = fmaxf(xx2 - xx1, 0.0f);
        float ih = fmaxf(yy2 - yy1, 0.0f);
        float inter = __fmul_rn(iw, ih);
        float aj = __fmul_rn(bj.z - bj.x, bj.w - bj.y);
        float uni = (ai + aj) - inter;
        float iou = inter / (uni + 1e-9f);
        if (iou > 0.45f && jc < r) {
            if (jj < 64) w0 |= 1ull << jj;
            else         w1 |= 1ull << (jj - 64);
        }
    }
    size_t rowbase = ((size_t)(b << 9) + r) * 8 + q * 2;
    ioug[rowbase]     = w0;
    ioug[rowbase + 1] = w1;
}

// ---------------- Kernel C3: sequential greedy scan + output ----------------
// One wave. Keep-mask words live in lanes 0..7; validity is i<nval (topkeys sorted).
// Row words prefetched 8-16 steps ahead into registers (ping-pong), branch-free.
__global__ __launch_bounds__(64) void scan_kernel(const unsigned long long* __restrict__ ioug,
                                                  const int* __restrict__ nvalid,
                                                  const float4* __restrict__ boxraw,
                                                  const float4* __restrict__ meta,
                                                  float* __restrict__ out) {
    int b = blockIdx.x, t = threadIdx.x;
    __shared__ unsigned long long sl[528 * 8];      // 33,792 B (512 rows + 16 pad rows)
    __shared__ unsigned long long skeep[8];

    // stage bitmatrix global -> LDS (16B per lane per iter)
    const ulonglong2* src = (const ulonglong2*)(ioug + ((size_t)b << 12));
    ulonglong2* dst = (ulonglong2*)sl;
    for (int it = 0; it < 32; it++) dst[it * 64 + t] = src[it * 64 + t];
    sl[4096 + t] = 0ull;                            // zero 16 pad rows (128 words)
    sl[4160 + t] = 0ull;
    __syncthreads();

    int w8 = t & 7;
    int nval = nvalid[b];
    unsigned long long keepW = 0ull;

#define STEP(ii, rwreg) { \
        bool hit = ((rwreg) & keepW) != 0ull; \
        unsigned long long bal = __ballot(hit); \
        bool kept = (bal == 0ull) && ((ii) < nval); \
        unsigned long long sb_ = (kept && (t == ((ii) >> 6))) ? (1ull << ((ii) & 63)) : 0ull; \
        keepW |= sb_; }

    unsigned long long A[8], Bf[8];
#pragma unroll
    for (int k = 0; k < 8; k++) A[k] = sl[(size_t)(0 + k) * 8 + w8];
#pragma unroll
    for (int k = 0; k < 8; k++) Bf[k] = sl[(size_t)(8 + k) * 8 + w8];
    for (int g = 0; g < 64; g += 2) {
        int base = g * 8;
#pragma unroll
        for (int k = 0; k < 8; k++) { STEP(base + k, A[k]); }
#pragma unroll
        for (int k = 0; k < 8; k++) A[k] = sl[(size_t)(base + 16 + k) * 8 + w8];
#pragma unroll
        for (int k = 0; k < 8; k++) { STEP(base + 8 + k, Bf[k]); }
#pragma unroll
        for (int k = 0; k < 8; k++) Bf[k] = sl[(size_t)(base + 24 + k) * 8 + w8];
    }
#undef STEP

    if (t < 8) skeep[t] = keepW;
    __syncthreads();

    // zero output region
    float* dets = out + (size_t)b * (MAXOUT * 7);
    float* mask = out + (size_t)NB * MAXOUT * 7 + (size_t)b * MAXOUT;
    for (int m = t; m < MAXOUT * 7; m += 64) dets[m] = 0.0f;
    for (int m = t; m < MAXOUT; m += 64) mask[m] = 0.0f;

    // rank kept rows, gather decoded data, write first 100
    for (int c = t; c < KPRE; c += 64) {
        int wq = c >> 6;
        unsigned long long kw = skeep[wq];
        int kept_c = (int)((kw >> (c & 63)) & 1ull);
        if (!kept_c) continue;
        int rank = 0;
        for (int w2 = 0; w2 < wq; w2++) rank += __popcll(skeep[w2]);
        rank += __popcll(kw & ((1ull << (c & 63)) - 1ull));
        if (rank < MAXOUT) {
            float4 rb = boxraw[(size_t)(b << 9) + c];
            float4 mt = meta[(size_t)(b << 9) + c];
            float* row = dets + rank * 7;
            row[0] = rb.x; row[1] = rb.y; row[2] = rb.z; row[3] = rb.w;
            row[4] = mt.x; row[5] = mt.y; row[6] = mt.z;
            mask[rank] = 1.0f;
        }
    }
}

extern "C" void kernel_launch(void* const* d_in, const int* in_sizes, int n_in,
                              void* d_out, int out_size, void* d_ws, size_t ws_size,
                              hipStream_t stream) {
    const float* pred = (const float*)d_in[0];
    float* out = (float*)d_out;

    char* ws = (char*)d_ws;
    unsigned* smax = (unsigned*)ws;                                    // 128
    int* nvalid = (int*)(ws + 128);                                    // 128
    float* scores = (float*)(ws + 256);                                // 1,075,200
    unsigned long long* topkeys = (unsigned long long*)(ws + 1075456); // 131,072
    float4* boxoff = (float4*)(ws + 1206528);                          // 262,144
    float4* boxraw = (float4*)(ws + 1468672);                          // 262,144
    float4* meta   = (float4*)(ws + 1730816);                          // 262,144
    unsigned long long* ioug = (unsigned long long*)(ws + 1992960);    // 1,048,576

    hipMemsetAsync(smax, 0, NB * sizeof(unsigned), stream);

    dim3 gA((NN + 127) / 128, NB);
    score_kernel<<<gA, 128, 0, stream>>>(pred, scores, smax);
    select_kernel<<<NB, 256, 0, stream>>>(scores, smax, topkeys, nvalid);
    decode_kernel<<<NB, 512, 0, stream>>>(pred, topkeys, boxoff, boxraw, meta);
    dim3 gI(8, NB);
    iou_kernel<<<gI, 256, 0, stream>>>(boxoff, ioug);
    scan_kernel<<<NB, 64, 0, stream>>>(ioug, nvalid, boxraw, meta, out);
}